// Round 8
// baseline (164.887 us; speedup 1.0000x reference)
//
#include <hip/hip_runtime.h>

typedef unsigned short u16;
typedef __attribute__((ext_vector_type(4))) float f32x4;
typedef __attribute__((ext_vector_type(8))) short bf16x8;
typedef __attribute__((ext_vector_type(4))) u16 u16x4;
typedef __attribute__((ext_vector_type(8))) u16 u16x8;

__device__ __forceinline__ u16 f2bf(float f) {
    unsigned u = __float_as_uint(f);
    unsigned r = (u + 0x7FFFu + ((u >> 16) & 1u)) >> 16;
    return (u16)r;
}

__device__ __forceinline__ void gld16(const void* g, void* l) {
    __builtin_amdgcn_global_load_lds(
        (const __attribute__((address_space(1))) unsigned*)g,
        (__attribute__((address_space(3))) unsigned*)l,
        16, 0, 0);
}

// ---------------- cast fp32 -> bf16, vectorized ----------------
__global__ __launch_bounds__(256) void cast_kernel(const float* __restrict__ in,
                                                   u16* __restrict__ out, int n4) {
    int i = blockIdx.x * blockDim.x + threadIdx.x;
    int stride = gridDim.x * blockDim.x;
    for (; i < n4; i += stride) {
        f32x4 v = ((const f32x4*)in)[i];
        u16x4 o;
        o[0] = f2bf(v[0]); o[1] = f2bf(v[1]); o[2] = f2bf(v[2]); o[3] = f2bf(v[3]);
        ((u16x4*)out)[i] = o;
    }
}

__global__ __launch_bounds__(256) void zero_kernel(float* __restrict__ p, int n) {
    int i = blockIdx.x * blockDim.x + threadIdx.x;
    if (i < n) p[i] = 0.f;
}

// ======== 128x128 single-barrier-per-phase bf16 GEMM: C = A[M,K]*B[N,K]^T ========
// 256 threads = 4 waves (2M x 2N), per-wave C = 64x64 (4x4 16x16 frags).
// BK=64, LDS 64KB static -> 2 blocks/CU: cross-block overlap hides the
// wave-wide barrier/lgkm/vmcnt stalls that capped the 128KB 256x256 version
// at 28% MfmaUtil (1 block/CU = nothing to run during stalls).
// XOR-swizzled 16B slots (slot ^= row&7), pre-swizzled global source, linear
// gld16 dest (rule 21). Single barrier per phase (before MFMA).
// Hazards: each wave reads its A-half at P1(m01)+P3(m23) -> A drains P3;
// its B-half at P1(n01)+P2(n23) -> B drains P2. Gap-2 stage slots:
//   P1: (t+1).Ah0, P2: (t+1).Ah1  [A buf db^1; last read t-1.P3]
//   P4: (t+2).Bh0+Bh1             [B buf db; last read t.P2]
// vmcnt(4) at P4 drains A(t+1)+B(t+1), leaves B(t+2)'s 4 loads in flight;
// vmcnt(0) when t+2>=NT (also covers A(NT-1) residency for the last iter).
// EPI 0: C = bf16(acc*scale)
// EPI 2: C = bf16(exp(acc*scale)); atomicAdd row sums into denom[z*2048+row]
//        (softmax without max-shift: |scores|/32 <= ~2 for this data)
// EPI 3: C = fp32(acc / denom[z*2048+row])
template <int EPI>
__global__ __launch_bounds__(256, 2) void gemm128(
    const u16* __restrict__ A, const u16* __restrict__ Bm, void* __restrict__ Cv,
    int K, int lda, int ldb, int ldc,
    long long sA, long long sB, long long sC, float scale,
    float* __restrict__ denom) {
    __shared__ __align__(16) char smem[65536];  // A: 2x16KB, B: 2x16KB
    const u16* Ab = A + (long long)blockIdx.z * sA;
    const u16* Bb = Bm + (long long)blockIdx.z * sB;

    const int tid  = threadIdx.x;
    const int lane = tid & 63;
    const int w    = tid >> 6;   // 0..3
    const int wm   = w >> 1;     // 0..1
    const int wn   = w & 1;      // 0..1
    const int rowBase = blockIdx.x << 7;
    const int colBase = blockIdx.y << 7;
    const int NT = K >> 6;       // requires NT >= 2
    const int aRow = lane & 15;

    // half-tiles: h0=Ah0(rows 0-63), h3=Ah1(64-127), h1=Bh0, h2=Bh1.
    // each = 64 rows x 128B = 8KB = 2 gld16 issues (256 thr x 16B = 4KB).
    auto stage = [&](int tile, int h) {
        if (tile >= NT) return;
        const int db = tile & 1;
        const int kt = tile << 6;
        const u16* mat; int ldm, rb, halfRow; char* region;
        if (h == 0)      { mat = Ab; ldm = lda; rb = rowBase; halfRow = 0;  region = smem + db * 16384; }
        else if (h == 3) { mat = Ab; ldm = lda; rb = rowBase; halfRow = 64; region = smem + db * 16384; }
        else if (h == 1) { mat = Bb; ldm = ldb; rb = colBase; halfRow = 0;  region = smem + 32768 + db * 16384; }
        else             { mat = Bb; ldm = ldb; rb = colBase; halfRow = 64; region = smem + 32768 + db * 16384; }
#pragma unroll
        for (int i = 0; i < 2; i++) {
            int o    = i * 4096 + tid * 16;   // 0..8191 within the 8KB half
            int r    = o >> 7;                 // 0..63 row within half
            int slot = (o >> 4) & 7;           // 16B slot in 128B row
            const u16* g = mat + (size_t)(rb + halfRow + r) * ldm + kt +
                           ((slot ^ (r & 7)) << 3);          // inverse-swizzled source
            gld16(g, region + halfRow * 128 + i * 4096 + (w << 10));  // wave-uniform dest
        }
    };
    auto ldA = [&](int db, int row, int ks) -> bf16x8 {
        int byte = db * 16384 + row * 128 + ((((ks << 2) | (lane >> 4)) ^ (row & 7)) << 4);
        return *(const bf16x8*)(smem + byte);
    };
    auto ldB = [&](int db, int row, int ks) -> bf16x8 {
        int byte = 32768 + db * 16384 + row * 128 + ((((ks << 2) | (lane >> 4)) ^ (row & 7)) << 4);
        return *(const bf16x8*)(smem + byte);
    };

    f32x4 acc[4][4] = {};
    bf16x8 aF[2][2], b0[2][2], b1[2][2];

    // prologue: tile0 all 4 halves (8 issues) + tile1's B halves (4 issues);
    // vmcnt(4) drains tile0, leaves B(1) in flight. A(1) staged in iter 0.
    stage(0, 0); stage(0, 3); stage(0, 1); stage(0, 2);
    stage(1, 1); stage(1, 2);
    __builtin_amdgcn_sched_barrier(0);
    asm volatile("s_waitcnt vmcnt(4)" ::: "memory");
    __builtin_amdgcn_sched_barrier(0);
    __builtin_amdgcn_s_barrier();

    for (int t = 0; t < NT; ++t) {
        const int db = t & 1;
        // ---- P1: read a[m01] + b[n01]; stage(t+1, Ah0); MFMA m01 x n01 ----
#pragma unroll
        for (int m = 0; m < 2; m++)
#pragma unroll
            for (int ks = 0; ks < 2; ks++)
                aF[m][ks] = ldA(db, wm * 64 + m * 16 + aRow, ks);
#pragma unroll
        for (int n = 0; n < 2; n++)
#pragma unroll
            for (int ks = 0; ks < 2; ks++)
                b0[n][ks] = ldB(db, wn * 64 + n * 16 + aRow, ks);
        stage(t + 1, 0);
        __builtin_amdgcn_s_barrier();
        asm volatile("s_waitcnt lgkmcnt(0)" ::: "memory");
        __builtin_amdgcn_sched_barrier(0);
        __builtin_amdgcn_s_setprio(1);
#pragma unroll
        for (int ks = 0; ks < 2; ks++)
#pragma unroll
            for (int m = 0; m < 2; m++)
#pragma unroll
                for (int n = 0; n < 2; n++)
                    acc[m][n] = __builtin_amdgcn_mfma_f32_16x16x32_bf16(
                        aF[m][ks], b0[n][ks], acc[m][n], 0, 0, 0);
        __builtin_amdgcn_s_setprio(0);
        // ---- P2: read b[n23]; stage(t+1, Ah1); MFMA m01 x n23 ----
#pragma unroll
        for (int n = 0; n < 2; n++)
#pragma unroll
            for (int ks = 0; ks < 2; ks++)
                b1[n][ks] = ldB(db, wn * 64 + (n + 2) * 16 + aRow, ks);
        stage(t + 1, 3);
        __builtin_amdgcn_s_barrier();
        asm volatile("s_waitcnt lgkmcnt(0)" ::: "memory");
        __builtin_amdgcn_sched_barrier(0);
        __builtin_amdgcn_s_setprio(1);
#pragma unroll
        for (int ks = 0; ks < 2; ks++)
#pragma unroll
            for (int m = 0; m < 2; m++)
#pragma unroll
                for (int n = 0; n < 2; n++)
                    acc[m][n + 2] = __builtin_amdgcn_mfma_f32_16x16x32_bf16(
                        aF[m][ks], b1[n][ks], acc[m][n + 2], 0, 0, 0);
        __builtin_amdgcn_s_setprio(0);
        // ---- P3: read a[m23]; MFMA m23 x n23 ----
#pragma unroll
        for (int m = 0; m < 2; m++)
#pragma unroll
            for (int ks = 0; ks < 2; ks++)
                aF[m][ks] = ldA(db, wm * 64 + (m + 2) * 16 + aRow, ks);
        __builtin_amdgcn_s_barrier();
        asm volatile("s_waitcnt lgkmcnt(0)" ::: "memory");
        __builtin_amdgcn_sched_barrier(0);
        __builtin_amdgcn_s_setprio(1);
#pragma unroll
        for (int ks = 0; ks < 2; ks++)
#pragma unroll
            for (int m = 0; m < 2; m++)
#pragma unroll
                for (int n = 0; n < 2; n++)
                    acc[m + 2][n + 2] = __builtin_amdgcn_mfma_f32_16x16x32_bf16(
                        aF[m][ks], b1[n][ks], acc[m + 2][n + 2], 0, 0, 0);
        __builtin_amdgcn_s_setprio(0);
        // ---- P4: stage(t+2, Bh0)+(t+2, Bh1); vmcnt; MFMA m23 x n01 ----
        stage(t + 2, 1);
        stage(t + 2, 2);
        __builtin_amdgcn_sched_barrier(0);
        if (t + 2 < NT) { asm volatile("s_waitcnt vmcnt(4)" ::: "memory"); }
        else            { asm volatile("s_waitcnt vmcnt(0)" ::: "memory"); }
        __builtin_amdgcn_sched_barrier(0);
        __builtin_amdgcn_s_barrier();
        __builtin_amdgcn_s_setprio(1);
#pragma unroll
        for (int ks = 0; ks < 2; ks++)
#pragma unroll
            for (int m = 0; m < 2; m++)
#pragma unroll
                for (int n = 0; n < 2; n++)
                    acc[m + 2][n] = __builtin_amdgcn_mfma_f32_16x16x32_bf16(
                        aF[m][ks], b0[n][ks], acc[m + 2][n], 0, 0, 0);
        __builtin_amdgcn_s_setprio(0);
    }

    // epilogue: C/D layout col = lane&15, row = (lane>>4)*4 + j
    const int row0 = rowBase + wm * 64 + ((lane >> 4) << 2);
    const int col0 = colBase + wn * 64 + (lane & 15);
    long long cb = (long long)blockIdx.z * sC;
    if (EPI == 0) {
#pragma unroll
        for (int m = 0; m < 4; m++)
#pragma unroll
            for (int n = 0; n < 4; n++) {
                f32x4 v = acc[m][n];
#pragma unroll
                for (int j = 0; j < 4; j++) {
                    size_t idx = (size_t)(row0 + m * 16 + j) * ldc + (col0 + n * 16);
                    ((u16*)Cv)[cb + idx] = f2bf(v[j] * scale);
                }
            }
    } else if (EPI == 2) {  // exp + row partial sums
        float* dz = denom + (long long)blockIdx.z * 2048;
#pragma unroll
        for (int m = 0; m < 4; m++) {
#pragma unroll
            for (int j = 0; j < 4; j++) {
                const int row = row0 + m * 16 + j;
                float rs = 0.f;
#pragma unroll
                for (int n = 0; n < 4; n++) {
                    float e = __expf(fminf(acc[m][n][j] * scale, 60.f));
                    rs += e;
                    ((u16*)Cv)[cb + (size_t)row * ldc + (col0 + n * 16)] = f2bf(e);
                }
#pragma unroll
                for (int off = 1; off < 16; off <<= 1) rs += __shfl_xor(rs, off);
                if ((lane & 15) == 0) atomicAdd(&dz[row], rs);
            }
        }
    } else {  // EPI == 3: fp32 out, divide by softmax denominator
        const float* dz = denom + (long long)blockIdx.z * 2048;
        float inv[4][4];
#pragma unroll
        for (int m = 0; m < 4; m++)
#pragma unroll
            for (int j = 0; j < 4; j++)
                inv[m][j] = 1.0f / dz[row0 + m * 16 + j];
#pragma unroll
        for (int m = 0; m < 4; m++)
#pragma unroll
            for (int n = 0; n < 4; n++) {
                f32x4 v = acc[m][n];
#pragma unroll
                for (int j = 0; j < 4; j++) {
                    size_t idx = (size_t)(row0 + m * 16 + j) * ldc + (col0 + n * 16);
                    ((float*)Cv)[cb + idx] = v[j] * inv[m][j];
                }
            }
    }
}

// ---------------- launch ----------------
extern "C" void kernel_launch(void* const* d_in, const int* in_sizes, int n_in,
                              void* d_out, int out_size, void* d_ws, size_t ws_size,
                              hipStream_t stream) {
    const float* x  = (const float*)d_in[0];
    const float* Wk = (const float*)d_in[1];
    const float* Wq = (const float*)d_in[2];
    const float* Wv = (const float*)d_in[3];
    float* out = (float*)d_out;
    char* ws = (char*)d_ws;
    const size_t MB = 1u << 20;

    u16* xb    = (u16*)(ws);             // 16MB [8192][1024]
    u16* Wqk   = (u16*)(ws + 16 * MB);   // 4MB  [2048][1024]: rows 0-1023 Wq, 1024-2047 Wk
    u16* Wvb   = (u16*)(ws + 20 * MB);   // 2MB
    float* den = (float*)(ws + 22 * MB); // 32KB [4][2048] softmax denominators
    u16* QK    = (u16*)(ws + 64 * MB);   // 32MB [8192][2048]: cols 0-1023 Q, 1024-2047 K
    u16* VT    = (u16*)(ws + 96 * MB);   // 16MB [1024][8192]: VT[o][b*2048+s]
    u16* Pb    = (u16*)(ws + 112 * MB);  // 32MB [4][2048][2048] unnormalized exp(scores)

    const long long SS = 2048LL * 2048;

    cast_kernel<<<2048, 256, 0, stream>>>(x, xb, 8388608 / 4);
    cast_kernel<<<1024, 256, 0, stream>>>(Wq, Wqk, 1048576 / 4);
    cast_kernel<<<1024, 256, 0, stream>>>(Wk, Wqk + 1048576, 1048576 / 4);
    cast_kernel<<<1024, 256, 0, stream>>>(Wv, Wvb, 1048576 / 4);
    zero_kernel<<<32, 256, 0, stream>>>(den, 8192);

    // [Q|K] = x @ [Wq|Wk]^T : M=8192, N=2048, K=1024 (1024 blocks)
    gemm128<0><<<dim3(64, 16, 1), 256, 0, stream>>>(
        xb, Wqk, QK, 1024, 1024, 1024, 2048, 0, 0, 0, 1.0f, nullptr);
    // V^T = Wv @ x^T : M=1024, N=8192, K=1024 (512 blocks)
    gemm128<0><<<dim3(8, 64, 1), 256, 0, stream>>>(
        Wvb, xb, VT, 1024, 1024, 1024, 8192, 0, 0, 0, 1.0f, nullptr);
    // P_unnorm = exp((Q @ K^T)/32), denom += row sums : per batch (1024 blocks)
    gemm128<2><<<dim3(16, 16, 4), 256, 0, stream>>>(
        QK, QK + 1024, Pb, 1024, 2048, 2048, 2048, SS, SS, SS, 0.03125f, den);
    // ctx = (P_unnorm @ (V^T)^T) / denom : per batch (512 blocks)
    gemm128<3><<<dim3(16, 8, 4), 256, 0, stream>>>(
        Pb, VT, out, 2048, 2048, 8192, 1024, SS, 2048LL, 2048LL * 1024, 1.0f, den);
}

// Round 9
// 159.778 us; speedup vs baseline: 1.0320x; 1.0320x over previous
//
#include <hip/hip_runtime.h>

typedef unsigned short u16;
typedef __attribute__((ext_vector_type(4))) float f32x4;
typedef __attribute__((ext_vector_type(8))) short bf16x8;
typedef __attribute__((ext_vector_type(4))) u16 u16x4;
typedef __attribute__((ext_vector_type(8))) u16 u16x8;

__device__ __forceinline__ u16 f2bf(float f) {
    unsigned u = __float_as_uint(f);
    unsigned r = (u + 0x7FFFu + ((u >> 16) & 1u)) >> 16;
    return (u16)r;
}

__device__ __forceinline__ void gld16(const void* g, void* l) {
    __builtin_amdgcn_global_load_lds(
        (const __attribute__((address_space(1))) unsigned*)g,
        (__attribute__((address_space(3))) unsigned*)l,
        16, 0, 0);
}

// ---------------- cast fp32 -> bf16, vectorized ----------------
__global__ __launch_bounds__(256) void cast_kernel(const float* __restrict__ in,
                                                   u16* __restrict__ out, int n4) {
    int i = blockIdx.x * blockDim.x + threadIdx.x;
    int stride = gridDim.x * blockDim.x;
    for (; i < n4; i += stride) {
        f32x4 v = ((const f32x4*)in)[i];
        u16x4 o;
        o[0] = f2bf(v[0]); o[1] = f2bf(v[1]); o[2] = f2bf(v[2]); o[3] = f2bf(v[3]);
        ((u16x4*)out)[i] = o;
    }
}

__global__ __launch_bounds__(256) void zero_kernel(float* __restrict__ p, int n) {
    int i = blockIdx.x * blockDim.x + threadIdx.x;
    if (i < n) p[i] = 0.f;
}

// ======== 256x256 reg-dbuf pipelined bf16 GEMM: C = A[M,K]*B[N,K]^T ========
// 8 waves (2M x 4N), per-wave 128x64. BK=64, LDS 128KB dbuf, XOR swizzle.
// ONE-PHASE-AHEAD REGISTER DOUBLE BUFFER: each phase issues the ds_reads for
// the NEXT phase's MFMA, waits with a COUNTED lgkmcnt (drains only the
// previous phase's reads, keeps this phase's in flight), so the LDS drain
// that serialized R5-R7 (lgkm0 over 12 fresh reads before every MFMA) is
// hidden under the previous MFMA cluster + barrier.
// Quadrants ordered Q00(a01xb01) Q01(a01xb23) Q10(a23xb01) Q11(a23xb23) so
// no register set is reloaded before its last consumer (WAR-free):
//   a01,b01 reloaded in P4 (last use P2/P3); b23 reloaded t+1.P1 (last use P4);
//   a23 reloaded t+1.P2 (last use P4).
// Reads/phase: P1 b23[4], P2 a23[8], P3 none, P4(post-barrier) a01,b01[12].
// lgkm: P1(4) drains t-1.P4's 12; P2(8) drains P1's 4; P3(0) drains P2's 8.
// Stage slots (unchanged from R5, hazards re-verified vs new barrier spots:
// every stage issues >=1 barrier after universal drain of its region):
//   P1: A(t+1)h0, P2: A(t+1)h1, P4: B(t+2)h0+h1; vmcnt(4) at P4 leaves only
//   B(t+2) in flight -> A(t+1),B(t+1) resident before the post-barrier reads.
// EPI 0: bf16(acc*scale). EPI 2: bf16(exp(acc*scale)) + atomicAdd row sums.
template <int EPI>
__global__ __launch_bounds__(512, 1) void gemm256(
    const u16* __restrict__ A, const u16* __restrict__ Bm, void* __restrict__ Cv,
    int K, int lda, int ldb, int ldc,
    long long sA, long long sB, long long sC, float scale,
    float* __restrict__ denom) {
    extern __shared__ char smem[];
    const u16* Ab = A + (long long)blockIdx.z * sA;
    const u16* Bb = Bm + (long long)blockIdx.z * sB;

    const int tid  = threadIdx.x;
    const int lane = tid & 63;
    const int w    = tid >> 6;
    const int wm   = w >> 2;   // 0..1
    const int wn   = w & 3;    // 0..3
    const int rowBase = blockIdx.x << 8;
    const int colBase = blockIdx.y << 8;
    const int NT = K >> 6;     // requires NT >= 2
    const int aRow = lane & 15;

    auto stage = [&](int tile, int h) {
        if (tile >= NT) return;
        const int db = tile & 1;
        const int kt = tile << 6;
        const u16* mat; int ldm, rb, halfRow; char* region;
        if (h == 0)      { mat = Ab; ldm = lda; rb = rowBase; halfRow = 0;   region = smem + db * 32768; }
        else if (h == 1) { mat = Bb; ldm = ldb; rb = colBase; halfRow = 0;   region = smem + 65536 + db * 32768; }
        else if (h == 2) { mat = Bb; ldm = ldb; rb = colBase; halfRow = 128; region = smem + 65536 + db * 32768; }
        else             { mat = Ab; ldm = lda; rb = rowBase; halfRow = 128; region = smem + db * 32768; }
#pragma unroll
        for (int i = 0; i < 2; i++) {
            int o    = ((i * 8 + w) << 10) + lane * 16;
            int r    = o >> 7;
            int slot = (o >> 4) & 7;
            const u16* g = mat + (size_t)(rb + halfRow + r) * ldm + kt +
                           ((slot ^ (r & 7)) << 3);
            gld16(g, region + halfRow * 128 + ((i * 8 + w) << 10));
        }
    };
    auto ldA = [&](int db, int row, int ks) -> bf16x8 {
        int byte = db * 32768 + row * 128 + ((((ks << 2) | (lane >> 4)) ^ (row & 7)) << 4);
        return *(const bf16x8*)(smem + byte);
    };
    auto ldB = [&](int db, int row, int ks) -> bf16x8 {
        int byte = 65536 + db * 32768 + row * 128 + ((((ks << 2) | (lane >> 4)) ^ (row & 7)) << 4);
        return *(const bf16x8*)(smem + byte);
    };

    f32x4 acc[8][4] = {};
    bf16x8 a01[4][2], a23[4][2], b01[2][2], b23[2][2];

    // prologue: stage A(0),B(0),B(1); vmcnt(4) -> tile0 resident; initial
    // reg subtile a01(0),b01(0) (drained by t=0.P1's lgkm(4)).
    stage(0, 0); stage(0, 3); stage(0, 1); stage(0, 2);
    stage(1, 1); stage(1, 2);
    __builtin_amdgcn_sched_barrier(0);
    asm volatile("s_waitcnt vmcnt(4)" ::: "memory");
    __builtin_amdgcn_sched_barrier(0);
    __builtin_amdgcn_s_barrier();
#pragma unroll
    for (int m = 0; m < 4; m++)
#pragma unroll
        for (int ks = 0; ks < 2; ks++)
            a01[m][ks] = ldA(0, wm * 128 + m * 16 + aRow, ks);
#pragma unroll
    for (int n = 0; n < 2; n++)
#pragma unroll
        for (int ks = 0; ks < 2; ks++)
            b01[n][ks] = ldB(0, wn * 64 + n * 16 + aRow, ks);

    for (int t = 0; t < NT; ++t) {
        const int db = t & 1;
        // ---- P1: read b23(t) [for P2]; stage A(t+1)h0; lgkm(4); Q00; BAR ----
#pragma unroll
        for (int n = 0; n < 2; n++)
#pragma unroll
            for (int ks = 0; ks < 2; ks++)
                b23[n][ks] = ldB(db, wn * 64 + (n + 2) * 16 + aRow, ks);
        stage(t + 1, 0);
        asm volatile("s_waitcnt lgkmcnt(4)" ::: "memory");
        __builtin_amdgcn_sched_barrier(0);
        __builtin_amdgcn_s_setprio(1);
#pragma unroll
        for (int ks = 0; ks < 2; ks++)
#pragma unroll
            for (int m = 0; m < 4; m++)
#pragma unroll
                for (int n = 0; n < 2; n++)
                    acc[m][n] = __builtin_amdgcn_mfma_f32_16x16x32_bf16(
                        a01[m][ks], b01[n][ks], acc[m][n], 0, 0, 0);
        __builtin_amdgcn_s_setprio(0);
        __builtin_amdgcn_s_barrier();
        // ---- P2: read a23(t) [for P3]; stage A(t+1)h1; lgkm(8); Q01; BAR ----
#pragma unroll
        for (int m = 0; m < 4; m++)
#pragma unroll
            for (int ks = 0; ks < 2; ks++)
                a23[m][ks] = ldA(db, wm * 128 + (m + 4) * 16 + aRow, ks);
        stage(t + 1, 3);
        asm volatile("s_waitcnt lgkmcnt(8)" ::: "memory");
        __builtin_amdgcn_sched_barrier(0);
        __builtin_amdgcn_s_setprio(1);
#pragma unroll
        for (int ks = 0; ks < 2; ks++)
#pragma unroll
            for (int m = 0; m < 4; m++)
#pragma unroll
                for (int n = 0; n < 2; n++)
                    acc[m][n + 2] = __builtin_amdgcn_mfma_f32_16x16x32_bf16(
                        a01[m][ks], b23[n][ks], acc[m][n + 2], 0, 0, 0);
        __builtin_amdgcn_s_setprio(0);
        __builtin_amdgcn_s_barrier();
        // ---- P3: lgkm(0) [a23 ready, had P2 to land]; Q10; BAR ----
        asm volatile("s_waitcnt lgkmcnt(0)" ::: "memory");
        __builtin_amdgcn_sched_barrier(0);
        __builtin_amdgcn_s_setprio(1);
#pragma unroll
        for (int ks = 0; ks < 2; ks++)
#pragma unroll
            for (int m = 0; m < 4; m++)
#pragma unroll
                for (int n = 0; n < 2; n++)
                    acc[m + 4][n] = __builtin_amdgcn_mfma_f32_16x16x32_bf16(
                        a23[m][ks], b01[n][ks], acc[m + 4][n], 0, 0, 0);
        __builtin_amdgcn_s_setprio(0);
        __builtin_amdgcn_s_barrier();
        // ---- P4: stage B(t+2); vmcnt; BAR; read a01,b01(t+1); Q11 ----
        stage(t + 2, 1);
        stage(t + 2, 2);
        __builtin_amdgcn_sched_barrier(0);
        if (t + 2 < NT) { asm volatile("s_waitcnt vmcnt(4)" ::: "memory"); }
        else            { asm volatile("s_waitcnt vmcnt(0)" ::: "memory"); }
        __builtin_amdgcn_sched_barrier(0);
        __builtin_amdgcn_s_barrier();
        if (t + 1 < NT) {
#pragma unroll
            for (int m = 0; m < 4; m++)
#pragma unroll
                for (int ks = 0; ks < 2; ks++)
                    a01[m][ks] = ldA(db ^ 1, wm * 128 + m * 16 + aRow, ks);
#pragma unroll
            for (int n = 0; n < 2; n++)
#pragma unroll
                for (int ks = 0; ks < 2; ks++)
                    b01[n][ks] = ldB(db ^ 1, wn * 64 + n * 16 + aRow, ks);
        }
        __builtin_amdgcn_sched_barrier(0);
        __builtin_amdgcn_s_setprio(1);
#pragma unroll
        for (int ks = 0; ks < 2; ks++)
#pragma unroll
            for (int m = 0; m < 4; m++)
#pragma unroll
                for (int n = 0; n < 2; n++)
                    acc[m + 4][n + 2] = __builtin_amdgcn_mfma_f32_16x16x32_bf16(
                        a23[m][ks], b23[n][ks], acc[m + 4][n + 2], 0, 0, 0);
        __builtin_amdgcn_s_setprio(0);
    }

    const int row0 = rowBase + wm * 128 + ((lane >> 4) << 2);
    const int col0 = colBase + wn * 64 + (lane & 15);
    long long cb = (long long)blockIdx.z * sC;
    if (EPI == 0) {
#pragma unroll
        for (int m = 0; m < 8; m++)
#pragma unroll
            for (int n = 0; n < 4; n++) {
                f32x4 v = acc[m][n];
#pragma unroll
                for (int j = 0; j < 4; j++) {
                    size_t idx = (size_t)(row0 + m * 16 + j) * ldc + (col0 + n * 16);
                    ((u16*)Cv)[cb + idx] = f2bf(v[j] * scale);
                }
            }
    } else {  // EPI == 2: exp + row partial sums
        float* dz = denom + (long long)blockIdx.z * 2048;
#pragma unroll
        for (int m = 0; m < 8; m++) {
#pragma unroll
            for (int j = 0; j < 4; j++) {
                const int row = row0 + m * 16 + j;
                float rs = 0.f;
#pragma unroll
                for (int n = 0; n < 4; n++) {
                    float e = __expf(fminf(acc[m][n][j] * scale, 60.f));
                    rs += e;
                    ((u16*)Cv)[cb + (size_t)row * ldc + (col0 + n * 16)] = f2bf(e);
                }
#pragma unroll
                for (int off = 1; off < 16; off <<= 1) rs += __shfl_xor(rs, off);
                if ((lane & 15) == 0) atomicAdd(&dz[row], rs);
            }
        }
    }
}

// ======== 256x128 reg-dbuf pipelined bf16 GEMM (same schedule) ========
// 8 waves (4M x 2N), per-wave 64x64. LDS 96KB: A 2x32KB, B 2x16KB.
// Reads/phase: P1 b23[4], P2 a23[4], P3 none, P4(post-bar) a01,b01[8].
// lgkm: P1(4), P2(4), P3(0). Stages: P1 Ah0[2], P2 Ah1[2], P4 B[2]; vmcnt(2).
// EPI 0: bf16. EPI 3: fp32 acc/denom (PV).
template <int EPI>
__global__ __launch_bounds__(512, 1) void gemm256n128(
    const u16* __restrict__ A, const u16* __restrict__ Bm, void* __restrict__ Cv,
    int K, int lda, int ldb, int ldc,
    long long sA, long long sB, long long sC, float scale,
    const float* __restrict__ denom) {
    extern __shared__ char smem[];
    const u16* Ab = A + (long long)blockIdx.z * sA;
    const u16* Bb = Bm + (long long)blockIdx.z * sB;

    const int tid  = threadIdx.x;
    const int lane = tid & 63;
    const int w    = tid >> 6;
    const int wm   = w >> 1;   // 0..3
    const int wn   = w & 1;    // 0..1
    const int rowBase = blockIdx.x << 8;
    const int colBase = blockIdx.y << 7;
    const int NT = K >> 6;
    const int aRow = lane & 15;

    auto stage = [&](int tile, int h) {
        if (tile >= NT) return;
        const int db = tile & 1;
        const int kt = tile << 6;
        if (h == 0 || h == 3) {
            const int halfRow = (h == 0) ? 0 : 128;
            char* region = smem + db * 32768;
#pragma unroll
            for (int i = 0; i < 2; i++) {
                int o    = i * 8192 + tid * 16;
                int r    = o >> 7;
                int slot = (o >> 4) & 7;
                const u16* g = Ab + (size_t)(rowBase + halfRow + r) * lda + kt +
                               ((slot ^ (r & 7)) << 3);
                gld16(g, region + halfRow * 128 + i * 8192 + (w << 10));
            }
        } else {
            const int halfRow = (h == 1) ? 0 : 64;
            char* region = smem + 65536 + db * 16384;
            int o    = tid * 16;
            int r    = o >> 7;
            int slot = (o >> 4) & 7;
            const u16* g = Bb + (size_t)(colBase + halfRow + r) * ldb + kt +
                           ((slot ^ (r & 7)) << 3);
            gld16(g, region + halfRow * 128 + (w << 10));
        }
    };
    auto ldA = [&](int db, int row, int ks) -> bf16x8 {
        int byte = db * 32768 + row * 128 + ((((ks << 2) | (lane >> 4)) ^ (row & 7)) << 4);
        return *(const bf16x8*)(smem + byte);
    };
    auto ldB = [&](int db, int row, int ks) -> bf16x8 {
        int byte = 65536 + db * 16384 + row * 128 + ((((ks << 2) | (lane >> 4)) ^ (row & 7)) << 4);
        return *(const bf16x8*)(smem + byte);
    };

    f32x4 acc[4][4] = {};
    bf16x8 a01[2][2], a23[2][2], b01[2][2], b23[2][2];

    stage(0, 0); stage(0, 3); stage(0, 1); stage(0, 2);
    stage(1, 1); stage(1, 2);
    __builtin_amdgcn_sched_barrier(0);
    asm volatile("s_waitcnt vmcnt(2)" ::: "memory");
    __builtin_amdgcn_sched_barrier(0);
    __builtin_amdgcn_s_barrier();
#pragma unroll
    for (int m = 0; m < 2; m++)
#pragma unroll
        for (int ks = 0; ks < 2; ks++)
            a01[m][ks] = ldA(0, wm * 64 + m * 16 + aRow, ks);
#pragma unroll
    for (int n = 0; n < 2; n++)
#pragma unroll
        for (int ks = 0; ks < 2; ks++)
            b01[n][ks] = ldB(0, wn * 64 + n * 16 + aRow, ks);

    for (int t = 0; t < NT; ++t) {
        const int db = t & 1;
        // ---- P1: read b23; stage A(t+1)h0; lgkm(4); Q00; BAR ----
#pragma unroll
        for (int n = 0; n < 2; n++)
#pragma unroll
            for (int ks = 0; ks < 2; ks++)
                b23[n][ks] = ldB(db, wn * 64 + (n + 2) * 16 + aRow, ks);
        stage(t + 1, 0);
        asm volatile("s_waitcnt lgkmcnt(4)" ::: "memory");
        __builtin_amdgcn_sched_barrier(0);
        __builtin_amdgcn_s_setprio(1);
#pragma unroll
        for (int ks = 0; ks < 2; ks++)
#pragma unroll
            for (int m = 0; m < 2; m++)
#pragma unroll
                for (int n = 0; n < 2; n++)
                    acc[m][n] = __builtin_amdgcn_mfma_f32_16x16x32_bf16(
                        a01[m][ks], b01[n][ks], acc[m][n], 0, 0, 0);
        __builtin_amdgcn_s_setprio(0);
        __builtin_amdgcn_s_barrier();
        // ---- P2: read a23; stage A(t+1)h1; lgkm(4); Q01; BAR ----
#pragma unroll
        for (int m = 0; m < 2; m++)
#pragma unroll
            for (int ks = 0; ks < 2; ks++)
                a23[m][ks] = ldA(db, wm * 64 + (m + 2) * 16 + aRow, ks);
        stage(t + 1, 3);
        asm volatile("s_waitcnt lgkmcnt(4)" ::: "memory");
        __builtin_amdgcn_sched_barrier(0);
        __builtin_amdgcn_s_setprio(1);
#pragma unroll
        for (int ks = 0; ks < 2; ks++)
#pragma unroll
            for (int m = 0; m < 2; m++)
#pragma unroll
                for (int n = 0; n < 2; n++)
                    acc[m][n + 2] = __builtin_amdgcn_mfma_f32_16x16x32_bf16(
                        a01[m][ks], b23[n][ks], acc[m][n + 2], 0, 0, 0);
        __builtin_amdgcn_s_setprio(0);
        __builtin_amdgcn_s_barrier();
        // ---- P3: lgkm(0); Q10; BAR ----
        asm volatile("s_waitcnt lgkmcnt(0)" ::: "memory");
        __builtin_amdgcn_sched_barrier(0);
        __builtin_amdgcn_s_setprio(1);
#pragma unroll
        for (int ks = 0; ks < 2; ks++)
#pragma unroll
            for (int m = 0; m < 2; m++)
#pragma unroll
                for (int n = 0; n < 2; n++)
                    acc[m + 2][n] = __builtin_amdgcn_mfma_f32_16x16x32_bf16(
                        a23[m][ks], b01[n][ks], acc[m + 2][n], 0, 0, 0);
        __builtin_amdgcn_s_setprio(0);
        __builtin_amdgcn_s_barrier();
        // ---- P4: stage B(t+2); vmcnt; BAR; read a01,b01(t+1); Q11 ----
        stage(t + 2, 1);
        stage(t + 2, 2);
        __builtin_amdgcn_sched_barrier(0);
        if (t + 2 < NT) { asm volatile("s_waitcnt vmcnt(2)" ::: "memory"); }
        else            { asm volatile("s_waitcnt vmcnt(0)" ::: "memory"); }
        __builtin_amdgcn_sched_barrier(0);
        __builtin_amdgcn_s_barrier();
        if (t + 1 < NT) {
#pragma unroll
            for (int m = 0; m < 2; m++)
#pragma unroll
                for (int ks = 0; ks < 2; ks++)
                    a01[m][ks] = ldA(db ^ 1, wm * 64 + m * 16 + aRow, ks);
#pragma unroll
            for (int n = 0; n < 2; n++)
#pragma unroll
                for (int ks = 0; ks < 2; ks++)
                    b01[n][ks] = ldB(db ^ 1, wn * 64 + n * 16 + aRow, ks);
        }
        __builtin_amdgcn_sched_barrier(0);
        __builtin_amdgcn_s_setprio(1);
#pragma unroll
        for (int ks = 0; ks < 2; ks++)
#pragma unroll
            for (int m = 0; m < 2; m++)
#pragma unroll
                for (int n = 0; n < 2; n++)
                    acc[m + 2][n + 2] = __builtin_amdgcn_mfma_f32_16x16x32_bf16(
                        a23[m][ks], b23[n][ks], acc[m + 2][n + 2], 0, 0, 0);
        __builtin_amdgcn_s_setprio(0);
    }

    const int row0 = rowBase + wm * 64 + ((lane >> 4) << 2);
    const int col0 = colBase + wn * 64 + (lane & 15);
    long long cb = (long long)blockIdx.z * sC;
    if (EPI == 0) {
#pragma unroll
        for (int m = 0; m < 4; m++)
#pragma unroll
            for (int n = 0; n < 4; n++) {
                f32x4 v = acc[m][n];
#pragma unroll
                for (int j = 0; j < 4; j++) {
                    size_t idx = (size_t)(row0 + m * 16 + j) * ldc + (col0 + n * 16);
                    ((u16*)Cv)[cb + idx] = f2bf(v[j] * scale);
                }
            }
    } else {  // EPI == 3: fp32 out, divide by softmax denominator
        const float* dz = denom + (long long)blockIdx.z * 2048;
        float inv[4][4];
#pragma unroll
        for (int m = 0; m < 4; m++)
#pragma unroll
            for (int j = 0; j < 4; j++)
                inv[m][j] = 1.0f / dz[row0 + m * 16 + j];
#pragma unroll
        for (int m = 0; m < 4; m++)
#pragma unroll
            for (int n = 0; n < 4; n++) {
                f32x4 v = acc[m][n];
#pragma unroll
                for (int j = 0; j < 4; j++) {
                    size_t idx = (size_t)(row0 + m * 16 + j) * ldc + (col0 + n * 16);
                    ((float*)Cv)[cb + idx] = v[j] * inv[m][j];
                }
            }
    }
}

// ---------------- launch ----------------
extern "C" void kernel_launch(void* const* d_in, const int* in_sizes, int n_in,
                              void* d_out, int out_size, void* d_ws, size_t ws_size,
                              hipStream_t stream) {
    const float* x  = (const float*)d_in[0];
    const float* Wk = (const float*)d_in[1];
    const float* Wq = (const float*)d_in[2];
    const float* Wv = (const float*)d_in[3];
    float* out = (float*)d_out;
    char* ws = (char*)d_ws;
    const size_t MB = 1u << 20;

    u16* xb    = (u16*)(ws);             // 16MB [8192][1024]
    u16* Wqk   = (u16*)(ws + 16 * MB);   // 4MB  [2048][1024]: rows 0-1023 Wq, 1024-2047 Wk
    u16* Wvb   = (u16*)(ws + 20 * MB);   // 2MB
    float* den = (float*)(ws + 22 * MB); // 32KB [4][2048] softmax denominators
    u16* QK    = (u16*)(ws + 64 * MB);   // 32MB [8192][2048]: cols 0-1023 Q, 1024-2047 K
    u16* VT    = (u16*)(ws + 96 * MB);   // 16MB [1024][8192]: VT[o][b*2048+s]
    u16* Pb    = (u16*)(ws + 112 * MB);  // 32MB [4][2048][2048] unnormalized exp(scores)

    const long long SS = 2048LL * 2048;

    hipFuncSetAttribute((const void*)gemm256<0>, hipFuncAttributeMaxDynamicSharedMemorySize, 131072);
    hipFuncSetAttribute((const void*)gemm256<2>, hipFuncAttributeMaxDynamicSharedMemorySize, 131072);
    hipFuncSetAttribute((const void*)gemm256n128<0>, hipFuncAttributeMaxDynamicSharedMemorySize, 98304);
    hipFuncSetAttribute((const void*)gemm256n128<3>, hipFuncAttributeMaxDynamicSharedMemorySize, 98304);

    cast_kernel<<<2048, 256, 0, stream>>>(x, xb, 8388608 / 4);
    cast_kernel<<<1024, 256, 0, stream>>>(Wq, Wqk, 1048576 / 4);
    cast_kernel<<<1024, 256, 0, stream>>>(Wk, Wqk + 1048576, 1048576 / 4);
    cast_kernel<<<1024, 256, 0, stream>>>(Wv, Wvb, 1048576 / 4);
    zero_kernel<<<32, 256, 0, stream>>>(den, 8192);

    // [Q|K] = x @ [Wq|Wk]^T : M=8192, N=2048, K=1024 (256 blocks)
    gemm256<0><<<dim3(32, 8, 1), 512, 131072, stream>>>(
        xb, Wqk, QK, 1024, 1024, 1024, 2048, 0, 0, 0, 1.0f, nullptr);
    // V^T = Wv @ x^T : M=1024, N=8192, K=1024 (256 blocks)
    gemm256n128<0><<<dim3(4, 64, 1), 512, 98304, stream>>>(
        Wvb, xb, VT, 1024, 1024, 1024, 8192, 0, 0, 0, 1.0f, nullptr);
    // P_unnorm = exp((Q @ K^T)/32), denom += row sums : per batch (256 blocks)
    gemm256<2><<<dim3(8, 8, 4), 512, 131072, stream>>>(
        QK, QK + 1024, Pb, 1024, 2048, 2048, 2048, SS, SS, SS, 0.03125f, den);
    // ctx = (P_unnorm @ (V^T)^T) / denom : per batch (256 blocks)
    gemm256n128<3><<<dim3(8, 8, 4), 512, 98304, stream>>>(
        Pb, VT, out, 2048, 2048, 8192, 1024, SS, 2048LL, 2048LL * 1024, 1.0f, den);
}